// Round 12
// baseline (206.074 us; speedup 1.0000x reference)
//
#include <hip/hip_runtime.h>

// MultiHeadSelfAttention  B=2 S=2048 D=1024 H=16 d=64, fp32 in/out.
// R19: GEMM1 reverted to R16 exact (R18's 1-barrier/4-buf: Occ 34% vs 45%,
//      59.6 vs 58.2 -- GEMM1 closed). GEMM2 gets the R15-proven 3-buffer
//      counted-vmcnt pipeline (stage t+2, raw barriers, setprio, fences);
//      gates are per-wave-class (A-waves 2 loads/tile -> vmcnt(4), B-waves
//      1 -> vmcnt(2); tails 2/1 then 0/0). LDS 36KB -> 2 blocks/CU kept.
//   Why: GEMM2 was the last kernel on the no-op __syncthreads dbuf (R14
//   lesson: compiler drains vmcnt(0) at every barrier).
// prep/attn byte-identical to R16.
// ws: Ksw 8M @0 | val_h 8M @8 | wq_t 6M @16 | wo_t 2M @22 | q_h 8M @24
//     | x_h 8M @32 | Vsw 8M @40   (total 48M, no aliasing)

#define D_MODEL 1024
#define NHEAD   16
#define HDIM    64
#define SEQ     2048
#define BATCH   2
#define NTOK    (BATCH * SEQ)

typedef float    f32x4  __attribute__((ext_vector_type(4)));
typedef float    f32x16 __attribute__((ext_vector_type(16)));
typedef _Float16 f16x8  __attribute__((ext_vector_type(8)));
typedef _Float16 f16x4  __attribute__((ext_vector_type(4)));

#define GLOBAL_LOAD_LDS16(gptr, lptr)                                            \
    __builtin_amdgcn_global_load_lds(                                            \
        (const __attribute__((address_space(1))) unsigned int*)(gptr),           \
        (__attribute__((address_space(3))) unsigned int*)(lptr), 16, 0, 0)

// ---------------- prep: x->fp16, W_qkv^T, W_out^T (one launch) ----------------
__global__ __launch_bounds__(256) void prep_kernel(
    const float* __restrict__ x, _Float16* __restrict__ xh,
    const float* __restrict__ Wqkv, _Float16* __restrict__ wq_t,
    const float* __restrict__ Wout, _Float16* __restrict__ wo_t)
{
    const int bx = blockIdx.x;
    const int tid = threadIdx.x;
    if (bx < 4096) {
        const int i = (bx * 256 + tid) * 4;
        const float4 v = *(const float4*)&x[i];
        f16x4 hh;
        hh[0] = (_Float16)v.x; hh[1] = (_Float16)v.y;
        hh[2] = (_Float16)v.z; hh[3] = (_Float16)v.w;
        *(f16x4*)&xh[i] = hh;
        return;
    }
    __shared__ float ts[64][65];
    const float* W; _Float16* Wt; int N, n0, k0;
    if (bx < 4096 + 768) {
        const int local = bx - 4096;
        W = Wqkv; Wt = wq_t; N = 3072;
        n0 = (local % 48) * 64; k0 = (local / 48) * 64;
    } else {
        const int local = bx - 4864;
        W = Wout; Wt = wo_t; N = 1024;
        n0 = (local % 16) * 64; k0 = (local / 16) * 64;
    }
    {
        const int r = tid >> 2, c = (tid & 3) << 4;
        const float* src = W + (size_t)(k0 + r) * N + n0 + c;
        #pragma unroll
        for (int u = 0; u < 4; ++u)
            *(float4*)&ts[r][c + u * 4] = *(const float4*)&src[u * 4];
    }
    __syncthreads();
    {
        const int n = tid >> 2, kg = (tid & 3) << 4;
        f16x8 v0, v1;
        #pragma unroll
        for (int j = 0; j < 8; ++j) {
            v0[j] = (_Float16)ts[kg + j][n];
            v1[j] = (_Float16)ts[kg + 8 + j][n];
        }
        _Float16* dst = Wt + (size_t)(n0 + n) * D_MODEL + k0 + kg;
        *(f16x8*)&dst[0] = v0;
        *(f16x8*)&dst[8] = v1;
    }
}

// ---------------- GEMM1: 128x128 tile, BK=32, 512 threads (8 waves of 32x64),
//   3-buffer counted-vmcnt pipeline; epilogue scatters Q/K/V to final layouts -
__global__ __launch_bounds__(512) void gemm_qkv_kernel(
    const _Float16* __restrict__ A, const _Float16* __restrict__ Bt,
    const float* __restrict__ bias, _Float16* __restrict__ Qh,
    _Float16* __restrict__ Ksw, _Float16* __restrict__ Vsw,
    int M, int N, int K)
{
    __shared__ _Float16 lds[3][2][4096];  // [buf3][plane A/B][chunk4][row128][8] 48KB
    const int tid = threadIdx.x;
    const int wave = tid >> 6, lane = tid & 63;
    const int quad = lane >> 4, l16 = lane & 15;
    const int m0 = blockIdx.y * 128, n0 = blockIdx.x * 128;
    const int wr = wave >> 1, wc = wave & 1;       // wave tile: rows wr*32, cols wc*64

    f32x4 acc[2][4] = {};

    const bool isA = wave < 4;
    const _Float16* gsrc = isA ? (A + (size_t)m0 * K) : (Bt + (size_t)n0 * K);
    const int plane = isA ? 0 : 1;
    const int sbase = (wave & 3) * 2;              // 2 segments of 1KB per wave

#define G1_STAGE(tt, bi) {                                                     \
        const int _k1 = (tt) * 32;                                             \
        _Pragma("unroll")                                                      \
        for (int _j = 0; _j < 2; ++_j) {                                       \
            const int _seg = sbase + _j;                                       \
            const int _row = ((_seg & 1) << 6) | lane;                         \
            GLOBAL_LOAD_LDS16(gsrc + (size_t)_row * K + _k1 + (_seg >> 1) * 8, \
                              &lds[bi][plane][_seg * 512]);                    \
        } }

#define G1_COMPUTE(bi) {                                                       \
        f16x8 a[2], b[4];                                                      \
        _Pragma("unroll")                                                      \
        for (int mt = 0; mt < 2; ++mt)                                         \
            a[mt] = *(const f16x8*)&lds[bi][0][quad * 1024 + (wr * 32 + mt * 16 + l16) * 8]; \
        _Pragma("unroll")                                                      \
        for (int nt = 0; nt < 4; ++nt)                                         \
            b[nt] = *(const f16x8*)&lds[bi][1][quad * 1024 + (wc * 64 + nt * 16 + l16) * 8]; \
        __builtin_amdgcn_s_setprio(1);                                         \
        _Pragma("unroll")                                                      \
        for (int mt = 0; mt < 2; ++mt)                                         \
            _Pragma("unroll")                                                  \
            for (int nt = 0; nt < 4; ++nt)                                     \
                acc[mt][nt] = __builtin_amdgcn_mfma_f32_16x16x32_f16(a[mt], b[nt], acc[mt][nt], 0, 0, 0); \
        __builtin_amdgcn_s_setprio(0); }

#define G1_KSTEP(t, gatestr) {                                                 \
        const int _cur = (t) % 3;                                              \
        if ((t) + 2 < nk) { G1_STAGE((t) + 2, ((t) + 2) % 3); }                \
        asm volatile("s_waitcnt " gatestr ::: "memory");                       \
        __builtin_amdgcn_s_barrier();                                          \
        __builtin_amdgcn_sched_barrier(0);                                     \
        G1_COMPUTE(_cur);                                                      \
        __builtin_amdgcn_sched_barrier(0);                                     \
        __builtin_amdgcn_s_barrier();                                          \
        __builtin_amdgcn_sched_barrier(0);                                     \
    }

    const int nk = K / 32;                 // 32
    G1_STAGE(0, 0);
    G1_STAGE(1, 1);

    for (int t = 0; t < nk - 2; ++t)
        G1_KSTEP(t, "vmcnt(4)");
    G1_KSTEP(nk - 2, "vmcnt(2)");
    G1_KSTEP(nk - 1, "vmcnt(0)");

#undef G1_KSTEP
#undef G1_COMPUTE
#undef G1_STAGE

    // ---- epilogue: 64-col region (64-aligned) mod 192 selects Q/K/V of head h
    const int colb = n0 + wc * 64;
    const int kind = (colb >> 6) % 3;      // 0=Q, 1=K, 2=V
    const int h    = colb / 192;
    const int bb   = m0 >> 11;             // batch (128-row tile within one batch)
    const int m0r  = m0 & 2047;            // s base within batch
    const size_t hsz = (size_t)8 * SEQ * 8;

    if (kind == 0) {
        // Q -> q_h[4096][1024]: row-major, head-compacted
        _Float16* qh = Qh + (size_t)m0 * D_MODEL + h * HDIM;
        #pragma unroll
        for (int nt = 0; nt < 4; ++nt) {
            const float bv = bias[colb + nt * 16 + l16];
            #pragma unroll
            for (int mt = 0; mt < 2; ++mt) {
                #pragma unroll
                for (int r = 0; r < 4; ++r) {
                    const int row = wr * 32 + mt * 16 + quad * 4 + r;
                    qh[(size_t)row * D_MODEL + nt * 16 + l16] = (_Float16)(acc[mt][nt][r] + bv);
                }
            }
        }
    } else if (kind == 1) {
        // K(s,d) -> kh[(d>>3)*SEQ*8 + s*8 + (d&7)]
        _Float16* kh = Ksw + (size_t)(bb * NHEAD + h) * hsz;
        #pragma unroll
        for (int nt = 0; nt < 4; ++nt) {
            const int d = nt * 16 + l16;
            const float bv = bias[colb + nt * 16 + l16];
            _Float16* kd = kh + (size_t)(d >> 3) * (SEQ * 8) + (d & 7);
            #pragma unroll
            for (int mt = 0; mt < 2; ++mt) {
                #pragma unroll
                for (int r = 0; r < 4; ++r) {
                    const int s = m0r + wr * 32 + mt * 16 + quad * 4 + r;
                    kd[(size_t)s * 8] = (_Float16)(acc[mt][nt][r] + bv);
                }
            }
        }
    } else {
        // V(s,d) -> vh[(s>>3)*512 + d*8 + (s&7)]; 4 acc rows = contiguous f16x4
        _Float16* vh = Vsw + (size_t)(bb * NHEAD + h) * hsz;
        #pragma unroll
        for (int nt = 0; nt < 4; ++nt) {
            const int d = nt * 16 + l16;
            const float bv = bias[colb + nt * 16 + l16];
            #pragma unroll
            for (int mt = 0; mt < 2; ++mt) {
                const int s0 = m0r + wr * 32 + mt * 16 + quad * 4;
                f16x4 pk;
                #pragma unroll
                for (int r = 0; r < 4; ++r)
                    pk[r] = (_Float16)(acc[mt][nt][r] + bv);
                *(f16x4*)&vh[(size_t)(s0 >> 3) * 512 + d * 8 + (s0 & 7)] = pk;
            }
        }
    }
}

// ---------------- GEMM2: 128x64 tile, BK=32, 512 threads (8 waves of 32x32),
//   3-buffer counted-vmcnt pipeline (per-wave-class gates), fp32 out ----------
__global__ __launch_bounds__(512) void gemm_out_kernel(
    const _Float16* __restrict__ A, const _Float16* __restrict__ Bt,
    const float* __restrict__ bias, float* __restrict__ Cout)
{
    const int K = D_MODEL, N = D_MODEL;
    __shared__ _Float16 ldsA[3][4096];    // [buf][chunk4][row128][8] 8KB x3
    __shared__ _Float16 ldsB[3][2048];    // [buf][chunk4][row64][8]  4KB x3  (36KB)
    const int tid = threadIdx.x;
    const int wave = tid >> 6, lane = tid & 63;
    const int quad = lane >> 4, l16 = lane & 15;
    const int m0 = blockIdx.y * 128, n0 = blockIdx.x * 64;
    const int wr = wave >> 1, wc = wave & 1;       // wave tile: rows wr*32, cols wc*32

    f32x4 acc[2][2] = {};
    const bool isA = wave < 4;

// A-waves (0-3): 2 segs each; B-waves (4-7): 1 seg each.
#define G2_STAGE(tt, bi) {                                                     \
        const int _k1 = (tt) * 32;                                             \
        if (isA) {                                                             \
            _Pragma("unroll")                                                  \
            for (int _j = 0; _j < 2; ++_j) {                                   \
                const int _seg = wave * 2 + _j;                                \
                const int _row = ((_seg & 1) << 6) | lane;                     \
                GLOBAL_LOAD_LDS16(A + (size_t)(m0 + _row) * K + _k1 + (_seg >> 1) * 8, \
                                  &ldsA[bi][_seg * 512]);                      \
            }                                                                  \
        } else {                                                               \
            const int _seg = wave - 4;                                         \
            GLOBAL_LOAD_LDS16(Bt + (size_t)(n0 + lane) * K + _k1 + _seg * 8,   \
                              &ldsB[bi][_seg * 512]);                          \
        } }

#define G2_COMPUTE(bi) {                                                       \
        f16x8 a[2], b[2];                                                      \
        _Pragma("unroll")                                                      \
        for (int mt = 0; mt < 2; ++mt)                                         \
            a[mt] = *(const f16x8*)&ldsA[bi][quad * 1024 + (wr * 32 + mt * 16 + l16) * 8]; \
        _Pragma("unroll")                                                      \
        for (int nt = 0; nt < 2; ++nt)                                         \
            b[nt] = *(const f16x8*)&ldsB[bi][quad * 512 + (wc * 32 + nt * 16 + l16) * 8]; \
        __builtin_amdgcn_s_setprio(1);                                         \
        _Pragma("unroll")                                                      \
        for (int mt = 0; mt < 2; ++mt)                                         \
            _Pragma("unroll")                                                  \
            for (int nt = 0; nt < 2; ++nt)                                     \
                acc[mt][nt] = __builtin_amdgcn_mfma_f32_16x16x32_f16(a[mt], b[nt], acc[mt][nt], 0, 0, 0); \
        __builtin_amdgcn_s_setprio(0); }

// Same R15 structure/safety: stage t+2 | per-class gate | barrier | compute |
// barrier. Gate counts: A-waves 2 loads/tile (2 tiles in flight -> 4),
// B-waves 1 (-> 2). sched_barrier(0) pins reads (rule-18).
#define G2_KSTEP(t, gA, gB) {                                                  \
        const int _cur = (t) % 3;                                              \
        if ((t) + 2 < nk) { G2_STAGE((t) + 2, ((t) + 2) % 3); }                \
        if (isA) { asm volatile("s_waitcnt " gA ::: "memory"); }               \
        else     { asm volatile("s_waitcnt " gB ::: "memory"); }               \
        __builtin_amdgcn_s_barrier();                                          \
        __builtin_amdgcn_sched_barrier(0);                                     \
        G2_COMPUTE(_cur);                                                      \
        __builtin_amdgcn_sched_barrier(0);                                     \
        __builtin_amdgcn_s_barrier();                                          \
        __builtin_amdgcn_sched_barrier(0);                                     \
    }

    const int nk = K / 32;                 // 32
    G2_STAGE(0, 0);
    G2_STAGE(1, 1);

    for (int t = 0; t < nk - 2; ++t)
        G2_KSTEP(t, "vmcnt(4)", "vmcnt(2)");
    G2_KSTEP(nk - 2, "vmcnt(2)", "vmcnt(1)");
    G2_KSTEP(nk - 1, "vmcnt(0)", "vmcnt(0)");

#undef G2_KSTEP
#undef G2_COMPUTE
#undef G2_STAGE

    #pragma unroll
    for (int nt = 0; nt < 2; ++nt) {
        const int col = n0 + wc * 32 + nt * 16 + l16;
        const float bv = bias[col];
        #pragma unroll
        for (int mt = 0; mt < 2; ++mt) {
            #pragma unroll
            for (int r = 0; r < 4; ++r) {
                const int row = m0 + wr * 32 + mt * 16 + quad * 4 + r;
                Cout[(size_t)row * N + col] = acc[mt][nt][r] + bv;
            }
        }
    }
}

// softmax fragment: s0/s1 (keys 0-31 / 32-63 scores for q=l31) -> 4 PV A-frags
// pa[ks][j] = P[q=l31][key = ks*16 + hi*8 + j], rs += sum of own 32 exp2's.
__device__ __forceinline__ void softmax_frag(
    const f32x16 s0, const f32x16 s1, float& rs, f16x8 pa[4])
{
    #pragma unroll
    for (int half = 0; half < 2; ++half) {
        const f32x16 sv = half ? s1 : s0;
        float p[16];
        #pragma unroll
        for (int r = 0; r < 16; ++r)
            p[r] = __builtin_amdgcn_exp2f(sv[r]);
        #pragma unroll
        for (int r = 0; r < 16; r += 4)
            rs += (p[r] + p[r + 1]) + (p[r + 2] + p[r + 3]);

        union { f16x8 hv; unsigned u[4]; } lo, hh;
        {
            const unsigned A = __builtin_bit_cast(unsigned, __builtin_amdgcn_cvt_pkrtz(p[0], p[1]));
            const unsigned B = __builtin_bit_cast(unsigned, __builtin_amdgcn_cvt_pkrtz(p[2], p[3]));
            const unsigned C = __builtin_bit_cast(unsigned, __builtin_amdgcn_cvt_pkrtz(p[4], p[5]));
            const unsigned D = __builtin_bit_cast(unsigned, __builtin_amdgcn_cvt_pkrtz(p[6], p[7]));
            const auto rac = __builtin_amdgcn_permlane32_swap(A, C, false, false);
            const auto rbd = __builtin_amdgcn_permlane32_swap(B, D, false, false);
            lo.u[0] = rac[0]; lo.u[1] = rbd[0]; lo.u[2] = rac[1]; lo.u[3] = rbd[1];
        }
        {
            const unsigned E = __builtin_bit_cast(unsigned, __builtin_amdgcn_cvt_pkrtz(p[8],  p[9]));
            const unsigned F = __builtin_bit_cast(unsigned, __builtin_amdgcn_cvt_pkrtz(p[10], p[11]));
            const unsigned G = __builtin_bit_cast(unsigned, __builtin_amdgcn_cvt_pkrtz(p[12], p[13]));
            const unsigned H = __builtin_bit_cast(unsigned, __builtin_amdgcn_cvt_pkrtz(p[14], p[15]));
            const auto reg = __builtin_amdgcn_permlane32_swap(E, G, false, false);
            const auto rfh = __builtin_amdgcn_permlane32_swap(F, H, false, false);
            hh.u[0] = reg[0]; hh.u[1] = rfh[0]; hh.u[2] = reg[1]; hh.u[3] = rfh[1];
        }
        pa[half * 2]     = lo.hv;
        pa[half * 2 + 1] = hh.hv;
    }
}

// ---------------- fp16 MFMA flash attention, 32x32, QBLK=256 (8 waves x 32q),
//                  KVBLK=128 (2x 64-key subtiles per barrier), dbuf K/V --------
__global__ __launch_bounds__(512) void attn_mfma_kernel(
    const _Float16* __restrict__ Qh,
    const _Float16* __restrict__ Ksw, const _Float16* __restrict__ Vsw,
    _Float16* __restrict__ val)
{
    __shared__ _Float16 Ks[2][8192];      // [sub2][dchunk8][key64][8]  16KB x2
    __shared__ _Float16 Vts[2][8192];     // [sub2][kchunk8][d64][8]    16KB x2

    const int tid = threadIdx.x;
    const int wave = tid >> 6, lane = tid & 63;
    const int l31 = lane & 31, hi = lane >> 5;

    // XCD-chunked swizzle: 256 blocks, 32/XCD = 4 heads x 8 qt -> K/V 2MB/XCD
    const int id = blockIdx.x;
    const int g  = (id & 7) * 32 + (id >> 3);
    const int qt = g & 7, hb = g >> 3;
    const int h  = hb & 15, b = hb >> 4;
    const int q0 = qt * 256;

    const size_t hsz = (size_t)8 * SEQ * 8;
    const _Float16* kh = Ksw + (size_t)(b * NHEAD + h) * hsz;
    const _Float16* vh = Vsw + (size_t)(b * NHEAD + h) * hsz;

    // Q B-fragments: col=l31 -> q row, k = kk*16 + hi*8 + j  (from compact q_h)
    f16x8 qf[4];
    {
        const int row = q0 + wave * 32 + l31;
        const _Float16* src = Qh + (size_t)(b * SEQ + row) * D_MODEL + h * HDIM + hi * 8;
        #pragma unroll
        for (int kk = 0; kk < 4; ++kk) {
            const f16x8 t = *(const f16x8*)(src + kk * 16);
            #pragma unroll
            for (int j = 0; j < 8; ++j)
                qf[kk][j] = (_Float16)((float)t[j] * 0.1803368802f);   // (1/8)*log2(e)
        }
    }

    f32x16 acc0 = {};      // O[q][d], dtile 0 (d = l31)
    f32x16 acc1 = {};      // dtile 1 (d = 32+l31)
    float rs = 0.f;

    // staging: 8 waves x 2 chunk-instrs each cover sub(2) x chunk(8) for K and V
    const int sidx0 = wave * 2;            // 0..14 even
    // prologue: stage 128-key tile 0 into buffer 0
    #pragma unroll
    for (int j = 0; j < 2; ++j) {
        const int idx = sidx0 + j;         // 0..15
        const int u = idx >> 3, c = idx & 7;
        GLOBAL_LOAD_LDS16(kh + ((size_t)c * SEQ + u * 64 + lane) * 8, &Ks[0][idx * 512]);
        GLOBAL_LOAD_LDS16(vh + ((size_t)(u * 8 + c) * HDIM + lane) * 8, &Vts[0][idx * 512]);
    }
    __syncthreads();

    for (int kt = 0; kt < SEQ / 128; ++kt) {
        const int cur = kt & 1;

        // stage tile kt+1 into the other buffer
        if (kt + 1 < SEQ / 128) {
            #pragma unroll
            for (int j = 0; j < 2; ++j) {
                const int idx = sidx0 + j;
                const int u = idx >> 3, c = idx & 7;
                GLOBAL_LOAD_LDS16(kh + ((size_t)c * SEQ + (kt + 1) * 128 + u * 64 + lane) * 8,
                                  &Ks[cur ^ 1][idx * 512]);
                GLOBAL_LOAD_LDS16(vh + ((size_t)((kt + 1) * 16 + u * 8 + c) * HDIM + lane) * 8,
                                  &Vts[cur ^ 1][idx * 512]);
            }
        }

        // ---- two 64-key subtiles ----
        #pragma unroll
        for (int u = 0; u < 2; ++u) {
            const _Float16* ksub = &Ks[cur][u * 4096];
            const _Float16* vsub = &Vts[cur][u * 4096];

            // QK^T: S^T tiles (keytile 0: keys 0-31, keytile 1: keys 32-63)
            f32x16 s0 = {}, s1 = {};
            __builtin_amdgcn_s_setprio(1);
            #pragma unroll
            for (int kk = 0; kk < 4; ++kk) {
                const f16x8 k0 = *(const f16x8*)&ksub[(kk * 2 + hi) * 512 + l31 * 8];
                const f16x8 k1 = *(const f16x8*)&ksub[(kk * 2 + hi) * 512 + (32 + l31) * 8];
                s0 = __builtin_amdgcn_mfma_f32_32x32x16_f16(k0, qf[kk], s0, 0, 0, 0);
                s1 = __builtin_amdgcn_mfma_f32_32x32x16_f16(k1, qf[kk], s1, 0, 0, 0);
            }
            __builtin_amdgcn_s_setprio(0);

            // exp2 + in-register transpose to PV A-frags
            f16x8 pa[4];
            softmax_frag(s0, s1, rs, pa);

            // PV: O[q][d] += P[q][k] V[k][d], 4 ksteps of 16 keys
            __builtin_amdgcn_s_setprio(1);
            #pragma unroll
            for (int ks = 0; ks < 4; ++ks) {
                const f16x8 v0 = *(const f16x8*)&vsub[(ks * 2 + hi) * 512 + l31 * 8];
                const f16x8 v1 = *(const f16x8*)&vsub[(ks * 2 + hi) * 512 + (32 + l31) * 8];
                acc0 = __builtin_amdgcn_mfma_f32_32x32x16_f16(pa[ks], v0, acc0, 0, 0, 0);
                acc1 = __builtin_amdgcn_mfma_f32_32x32x16_f16(pa[ks], v1, acc1, 0, 0, 0);
            }
            __builtin_amdgcn_s_setprio(0);
        }

        __syncthreads();
    }

    // lane covers half the keys for q=l31; partner lane^32 has the complement
    rs += __shfl_xor(rs, 32);
    const float inv = 1.f / rs;

    #pragma unroll
    for (int r = 0; r < 16; ++r) {
        const int qo = (r & 3) + 8 * (r >> 2) + 4 * hi;     // wave-local q row
        const float invr = __shfl(inv, qo);                  // lane qo holds inv for q=qo
        const int row = b * SEQ + q0 + wave * 32 + qo;
        val[(size_t)row * D_MODEL + h * HDIM + l31]      = (_Float16)(acc0[r] * invr);
        val[(size_t)row * D_MODEL + h * HDIM + 32 + l31] = (_Float16)(acc1[r] * invr);
    }
}

extern "C" void kernel_launch(void* const* d_in, const int* in_sizes, int n_in,
                              void* d_out, int out_size, void* d_ws, size_t ws_size,
                              hipStream_t stream)
{
    const float* x     = (const float*)d_in[0];
    const float* W_qkv = (const float*)d_in[1];
    const float* b_qkv = (const float*)d_in[2];
    const float* W_out = (const float*)d_in[3];
    const float* b_out = (const float*)d_in[4];

    char* ws = (char*)d_ws;
    _Float16* Ksw   = (_Float16*)ws;                      // [32][8][2048][8]  8 MiB
    _Float16* val_h = (_Float16*)(ws + (8u << 20));       // [4096][1024]      8 MiB
    _Float16* wq_t  = (_Float16*)(ws + (16u << 20));      // [3072][1024]      6 MiB
    _Float16* wo_t  = (_Float16*)(ws + (22u << 20));      // [1024][1024]      2 MiB
    _Float16* q_h   = (_Float16*)(ws + (24u << 20));      // [4096][1024]      8 MiB
    _Float16* x_h   = (_Float16*)(ws + (32u << 20));      // [4096][1024]      8 MiB
    _Float16* Vsw   = (_Float16*)(ws + (40u << 20));      // [32][256][64][8]  8 MiB

    prep_kernel<<<5120, 256, 0, stream>>>(x, x_h, W_qkv, wq_t, W_out, wo_t);
    gemm_qkv_kernel<<<dim3(3 * D_MODEL / 128, NTOK / 128), 512, 0, stream>>>(
        x_h, wq_t, b_qkv, q_h, Ksw, Vsw, NTOK, 3 * D_MODEL, D_MODEL);
    attn_mfma_kernel<<<dim3(256, 1, 1), 512, 0, stream>>>(q_h, Ksw, Vsw, val_h);
    gemm_out_kernel<<<dim3(D_MODEL / 64, NTOK / 128), 512, 0, stream>>>(
        val_h, wo_t, b_out, (float*)d_out);
}

// Round 13
// 200.952 us; speedup vs baseline: 1.0255x; 1.0255x over previous
//
#include <hip/hip_runtime.h>

// MultiHeadSelfAttention  B=2 S=2048 D=1024 H=16 d=64, fp32 in/out.
// R20: GEMM2 reverted to R16's simple dbuf (R19's counted port: neutral-to
//      -3us -- regime-gate, GEMM2 closed). ATTN gets the one structural fix
//      left: 3-buffer ring + counted vmcnt(4) + ONE raw barrier per tile.
//      Old __syncthreads force-drained the 4 just-issued kt+1 prefetch loads
//      every iteration (R14 no-op-dbuf flaw). Now: stage(kt+1) -> vmcnt(4)
//      (own tile-kt loads drained, kt+1 in flight) -> s_barrier -> compute.
//      Safety: buf[x] read@kt, write-issued@kt+2 after barrier(kt+1), behind
//      which all reads are lgkm-drained. LDS 64->96KB, still 1 block/CU.
// GEMM1 = R16 exact (closed at ~58us). prep unchanged.
// ws: Ksw 8M @0 | val_h 8M @8 | wq_t 6M @16 | wo_t 2M @22 | q_h 8M @24
//     | x_h 8M @32 | Vsw 8M @40   (total 48M, no aliasing)

#define D_MODEL 1024
#define NHEAD   16
#define HDIM    64
#define SEQ     2048
#define BATCH   2
#define NTOK    (BATCH * SEQ)

typedef float    f32x4  __attribute__((ext_vector_type(4)));
typedef float    f32x16 __attribute__((ext_vector_type(16)));
typedef _Float16 f16x8  __attribute__((ext_vector_type(8)));
typedef _Float16 f16x4  __attribute__((ext_vector_type(4)));

#define GLOBAL_LOAD_LDS16(gptr, lptr)                                            \
    __builtin_amdgcn_global_load_lds(                                            \
        (const __attribute__((address_space(1))) unsigned int*)(gptr),           \
        (__attribute__((address_space(3))) unsigned int*)(lptr), 16, 0, 0)

// ---------------- prep: x->fp16, W_qkv^T, W_out^T (one launch) ----------------
__global__ __launch_bounds__(256) void prep_kernel(
    const float* __restrict__ x, _Float16* __restrict__ xh,
    const float* __restrict__ Wqkv, _Float16* __restrict__ wq_t,
    const float* __restrict__ Wout, _Float16* __restrict__ wo_t)
{
    const int bx = blockIdx.x;
    const int tid = threadIdx.x;
    if (bx < 4096) {
        const int i = (bx * 256 + tid) * 4;
        const float4 v = *(const float4*)&x[i];
        f16x4 hh;
        hh[0] = (_Float16)v.x; hh[1] = (_Float16)v.y;
        hh[2] = (_Float16)v.z; hh[3] = (_Float16)v.w;
        *(f16x4*)&xh[i] = hh;
        return;
    }
    __shared__ float ts[64][65];
    const float* W; _Float16* Wt; int N, n0, k0;
    if (bx < 4096 + 768) {
        const int local = bx - 4096;
        W = Wqkv; Wt = wq_t; N = 3072;
        n0 = (local % 48) * 64; k0 = (local / 48) * 64;
    } else {
        const int local = bx - 4864;
        W = Wout; Wt = wo_t; N = 1024;
        n0 = (local % 16) * 64; k0 = (local / 16) * 64;
    }
    {
        const int r = tid >> 2, c = (tid & 3) << 4;
        const float* src = W + (size_t)(k0 + r) * N + n0 + c;
        #pragma unroll
        for (int u = 0; u < 4; ++u)
            *(float4*)&ts[r][c + u * 4] = *(const float4*)&src[u * 4];
    }
    __syncthreads();
    {
        const int n = tid >> 2, kg = (tid & 3) << 4;
        f16x8 v0, v1;
        #pragma unroll
        for (int j = 0; j < 8; ++j) {
            v0[j] = (_Float16)ts[kg + j][n];
            v1[j] = (_Float16)ts[kg + 8 + j][n];
        }
        _Float16* dst = Wt + (size_t)(n0 + n) * D_MODEL + k0 + kg;
        *(f16x8*)&dst[0] = v0;
        *(f16x8*)&dst[8] = v1;
    }
}

// ---------------- GEMM1: 128x128 tile, BK=32, 512 threads (8 waves of 32x64),
//   3-buffer counted-vmcnt pipeline; epilogue scatters Q/K/V to final layouts -
__global__ __launch_bounds__(512) void gemm_qkv_kernel(
    const _Float16* __restrict__ A, const _Float16* __restrict__ Bt,
    const float* __restrict__ bias, _Float16* __restrict__ Qh,
    _Float16* __restrict__ Ksw, _Float16* __restrict__ Vsw,
    int M, int N, int K)
{
    __shared__ _Float16 lds[3][2][4096];  // [buf3][plane A/B][chunk4][row128][8] 48KB
    const int tid = threadIdx.x;
    const int wave = tid >> 6, lane = tid & 63;
    const int quad = lane >> 4, l16 = lane & 15;
    const int m0 = blockIdx.y * 128, n0 = blockIdx.x * 128;
    const int wr = wave >> 1, wc = wave & 1;       // wave tile: rows wr*32, cols wc*64

    f32x4 acc[2][4] = {};

    const bool isA = wave < 4;
    const _Float16* gsrc = isA ? (A + (size_t)m0 * K) : (Bt + (size_t)n0 * K);
    const int plane = isA ? 0 : 1;
    const int sbase = (wave & 3) * 2;              // 2 segments of 1KB per wave

#define G1_STAGE(tt, bi) {                                                     \
        const int _k1 = (tt) * 32;                                             \
        _Pragma("unroll")                                                      \
        for (int _j = 0; _j < 2; ++_j) {                                       \
            const int _seg = sbase + _j;                                       \
            const int _row = ((_seg & 1) << 6) | lane;                         \
            GLOBAL_LOAD_LDS16(gsrc + (size_t)_row * K + _k1 + (_seg >> 1) * 8, \
                              &lds[bi][plane][_seg * 512]);                    \
        } }

#define G1_COMPUTE(bi) {                                                       \
        f16x8 a[2], b[4];                                                      \
        _Pragma("unroll")                                                      \
        for (int mt = 0; mt < 2; ++mt)                                         \
            a[mt] = *(const f16x8*)&lds[bi][0][quad * 1024 + (wr * 32 + mt * 16 + l16) * 8]; \
        _Pragma("unroll")                                                      \
        for (int nt = 0; nt < 4; ++nt)                                         \
            b[nt] = *(const f16x8*)&lds[bi][1][quad * 1024 + (wc * 64 + nt * 16 + l16) * 8]; \
        __builtin_amdgcn_s_setprio(1);                                         \
        _Pragma("unroll")                                                      \
        for (int mt = 0; mt < 2; ++mt)                                         \
            _Pragma("unroll")                                                  \
            for (int nt = 0; nt < 4; ++nt)                                     \
                acc[mt][nt] = __builtin_amdgcn_mfma_f32_16x16x32_f16(a[mt], b[nt], acc[mt][nt], 0, 0, 0); \
        __builtin_amdgcn_s_setprio(0); }

#define G1_KSTEP(t, gatestr) {                                                 \
        const int _cur = (t) % 3;                                              \
        if ((t) + 2 < nk) { G1_STAGE((t) + 2, ((t) + 2) % 3); }                \
        asm volatile("s_waitcnt " gatestr ::: "memory");                       \
        __builtin_amdgcn_s_barrier();                                          \
        __builtin_amdgcn_sched_barrier(0);                                     \
        G1_COMPUTE(_cur);                                                      \
        __builtin_amdgcn_sched_barrier(0);                                     \
        __builtin_amdgcn_s_barrier();                                          \
        __builtin_amdgcn_sched_barrier(0);                                     \
    }

    const int nk = K / 32;                 // 32
    G1_STAGE(0, 0);
    G1_STAGE(1, 1);

    for (int t = 0; t < nk - 2; ++t)
        G1_KSTEP(t, "vmcnt(4)");
    G1_KSTEP(nk - 2, "vmcnt(2)");
    G1_KSTEP(nk - 1, "vmcnt(0)");

#undef G1_KSTEP
#undef G1_COMPUTE
#undef G1_STAGE

    // ---- epilogue: 64-col region (64-aligned) mod 192 selects Q/K/V of head h
    const int colb = n0 + wc * 64;
    const int kind = (colb >> 6) % 3;      // 0=Q, 1=K, 2=V
    const int h    = colb / 192;
    const int bb   = m0 >> 11;             // batch (128-row tile within one batch)
    const int m0r  = m0 & 2047;            // s base within batch
    const size_t hsz = (size_t)8 * SEQ * 8;

    if (kind == 0) {
        // Q -> q_h[4096][1024]: row-major, head-compacted
        _Float16* qh = Qh + (size_t)m0 * D_MODEL + h * HDIM;
        #pragma unroll
        for (int nt = 0; nt < 4; ++nt) {
            const float bv = bias[colb + nt * 16 + l16];
            #pragma unroll
            for (int mt = 0; mt < 2; ++mt) {
                #pragma unroll
                for (int r = 0; r < 4; ++r) {
                    const int row = wr * 32 + mt * 16 + quad * 4 + r;
                    qh[(size_t)row * D_MODEL + nt * 16 + l16] = (_Float16)(acc[mt][nt][r] + bv);
                }
            }
        }
    } else if (kind == 1) {
        // K(s,d) -> kh[(d>>3)*SEQ*8 + s*8 + (d&7)]
        _Float16* kh = Ksw + (size_t)(bb * NHEAD + h) * hsz;
        #pragma unroll
        for (int nt = 0; nt < 4; ++nt) {
            const int d = nt * 16 + l16;
            const float bv = bias[colb + nt * 16 + l16];
            _Float16* kd = kh + (size_t)(d >> 3) * (SEQ * 8) + (d & 7);
            #pragma unroll
            for (int mt = 0; mt < 2; ++mt) {
                #pragma unroll
                for (int r = 0; r < 4; ++r) {
                    const int s = m0r + wr * 32 + mt * 16 + quad * 4 + r;
                    kd[(size_t)s * 8] = (_Float16)(acc[mt][nt][r] + bv);
                }
            }
        }
    } else {
        // V(s,d) -> vh[(s>>3)*512 + d*8 + (s&7)]; 4 acc rows = contiguous f16x4
        _Float16* vh = Vsw + (size_t)(bb * NHEAD + h) * hsz;
        #pragma unroll
        for (int nt = 0; nt < 4; ++nt) {
            const int d = nt * 16 + l16;
            const float bv = bias[colb + nt * 16 + l16];
            #pragma unroll
            for (int mt = 0; mt < 2; ++mt) {
                const int s0 = m0r + wr * 32 + mt * 16 + quad * 4;
                f16x4 pk;
                #pragma unroll
                for (int r = 0; r < 4; ++r)
                    pk[r] = (_Float16)(acc[mt][nt][r] + bv);
                *(f16x4*)&vh[(size_t)(s0 >> 3) * 512 + d * 8 + (s0 & 7)] = pk;
            }
        }
    }
}

// ---------------- GEMM2: 128x64 tile, BK=32, 512 threads (8 waves of 32x32),
//                  double-buffered staging, one barrier per K-step, fp32 out --
__global__ __launch_bounds__(512) void gemm_out_kernel(
    const _Float16* __restrict__ A, const _Float16* __restrict__ Bt,
    const float* __restrict__ bias, float* __restrict__ Cout)
{
    const int K = D_MODEL, N = D_MODEL;
    __shared__ _Float16 ldsA[2][4096];    // [buf][chunk4][row128][8] 8KB x2
    __shared__ _Float16 ldsB[2][2048];    // [buf][chunk4][row64][8]  4KB x2
    const int tid = threadIdx.x;
    const int wave = tid >> 6, lane = tid & 63;
    const int quad = lane >> 4, l16 = lane & 15;
    const int m0 = blockIdx.y * 128, n0 = blockIdx.x * 64;
    const int wr = wave >> 1, wc = wave & 1;       // wave tile: rows wr*32, cols wc*32

    f32x4 acc[2][2] = {};

    // prologue: stage K-tile 0 into buf 0
    if (wave < 4) {
        #pragma unroll
        for (int j = 0; j < 2; ++j) {
            const int seg = wave * 2 + j;
            const int chunk = seg >> 1;
            const int row = ((seg & 1) << 6) | lane;
            GLOBAL_LOAD_LDS16(A + (size_t)(m0 + row) * K + chunk * 8, &ldsA[0][seg * 512]);
        }
    } else {
        const int seg = wave - 4;
        GLOBAL_LOAD_LDS16(Bt + (size_t)(n0 + lane) * K + seg * 8, &ldsB[0][seg * 512]);
    }
    __syncthreads();

    const int nk = K / 32;
    for (int t = 0; t < nk; ++t) {
        const int cur = t & 1;

        if (t + 1 < nk) {
            const int k1 = (t + 1) * 32;
            if (wave < 4) {
                #pragma unroll
                for (int j = 0; j < 2; ++j) {
                    const int seg = wave * 2 + j;
                    const int chunk = seg >> 1;
                    const int row = ((seg & 1) << 6) | lane;
                    GLOBAL_LOAD_LDS16(A + (size_t)(m0 + row) * K + k1 + chunk * 8,
                                      &ldsA[cur ^ 1][seg * 512]);
                }
            } else {
                const int seg = wave - 4;
                GLOBAL_LOAD_LDS16(Bt + (size_t)(n0 + lane) * K + k1 + seg * 8,
                                  &ldsB[cur ^ 1][seg * 512]);
            }
        }

        f16x8 a[2], b[2];
        #pragma unroll
        for (int mt = 0; mt < 2; ++mt)
            a[mt] = *(const f16x8*)&ldsA[cur][quad * 1024 + (wr * 32 + mt * 16 + l16) * 8];
        #pragma unroll
        for (int nt = 0; nt < 2; ++nt)
            b[nt] = *(const f16x8*)&ldsB[cur][quad * 512 + (wc * 32 + nt * 16 + l16) * 8];
        #pragma unroll
        for (int mt = 0; mt < 2; ++mt)
            #pragma unroll
            for (int nt = 0; nt < 2; ++nt)
                acc[mt][nt] = __builtin_amdgcn_mfma_f32_16x16x32_f16(a[mt], b[nt], acc[mt][nt], 0, 0, 0);

        __syncthreads();
    }

    #pragma unroll
    for (int nt = 0; nt < 2; ++nt) {
        const int col = n0 + wc * 32 + nt * 16 + l16;
        const float bv = bias[col];
        #pragma unroll
        for (int mt = 0; mt < 2; ++mt) {
            #pragma unroll
            for (int r = 0; r < 4; ++r) {
                const int row = m0 + wr * 32 + mt * 16 + quad * 4 + r;
                Cout[(size_t)row * N + col] = acc[mt][nt][r] + bv;
            }
        }
    }
}

// softmax fragment: s0/s1 (keys 0-31 / 32-63 scores for q=l31) -> 4 PV A-frags
// pa[ks][j] = P[q=l31][key = ks*16 + hi*8 + j], rs += sum of own 32 exp2's.
__device__ __forceinline__ void softmax_frag(
    const f32x16 s0, const f32x16 s1, float& rs, f16x8 pa[4])
{
    #pragma unroll
    for (int half = 0; half < 2; ++half) {
        const f32x16 sv = half ? s1 : s0;
        float p[16];
        #pragma unroll
        for (int r = 0; r < 16; ++r)
            p[r] = __builtin_amdgcn_exp2f(sv[r]);
        #pragma unroll
        for (int r = 0; r < 16; r += 4)
            rs += (p[r] + p[r + 1]) + (p[r + 2] + p[r + 3]);

        union { f16x8 hv; unsigned u[4]; } lo, hh;
        {
            const unsigned A = __builtin_bit_cast(unsigned, __builtin_amdgcn_cvt_pkrtz(p[0], p[1]));
            const unsigned B = __builtin_bit_cast(unsigned, __builtin_amdgcn_cvt_pkrtz(p[2], p[3]));
            const unsigned C = __builtin_bit_cast(unsigned, __builtin_amdgcn_cvt_pkrtz(p[4], p[5]));
            const unsigned D = __builtin_bit_cast(unsigned, __builtin_amdgcn_cvt_pkrtz(p[6], p[7]));
            const auto rac = __builtin_amdgcn_permlane32_swap(A, C, false, false);
            const auto rbd = __builtin_amdgcn_permlane32_swap(B, D, false, false);
            lo.u[0] = rac[0]; lo.u[1] = rbd[0]; lo.u[2] = rac[1]; lo.u[3] = rbd[1];
        }
        {
            const unsigned E = __builtin_bit_cast(unsigned, __builtin_amdgcn_cvt_pkrtz(p[8],  p[9]));
            const unsigned F = __builtin_bit_cast(unsigned, __builtin_amdgcn_cvt_pkrtz(p[10], p[11]));
            const unsigned G = __builtin_bit_cast(unsigned, __builtin_amdgcn_cvt_pkrtz(p[12], p[13]));
            const unsigned H = __builtin_bit_cast(unsigned, __builtin_amdgcn_cvt_pkrtz(p[14], p[15]));
            const auto reg = __builtin_amdgcn_permlane32_swap(E, G, false, false);
            const auto rfh = __builtin_amdgcn_permlane32_swap(F, H, false, false);
            hh.u[0] = reg[0]; hh.u[1] = rfh[0]; hh.u[2] = reg[1]; hh.u[3] = rfh[1];
        }
        pa[half * 2]     = lo.hv;
        pa[half * 2 + 1] = hh.hv;
    }
}

// ---------------- fp16 MFMA flash attention, 32x32, QBLK=256 (8 waves x 32q),
//   KVBLK=128, 3-buffer ring + counted vmcnt(4) + ONE raw barrier per tile ----
__global__ __launch_bounds__(512) void attn_mfma_kernel(
    const _Float16* __restrict__ Qh,
    const _Float16* __restrict__ Ksw, const _Float16* __restrict__ Vsw,
    _Float16* __restrict__ val)
{
    __shared__ _Float16 Ks[3][8192];      // [buf3][sub2][dchunk8][key64][8]  48KB
    __shared__ _Float16 Vts[3][8192];     // [buf3][sub2][kchunk8][d64][8]    48KB

    const int tid = threadIdx.x;
    const int wave = tid >> 6, lane = tid & 63;
    const int l31 = lane & 31, hi = lane >> 5;

    // XCD-chunked swizzle: 256 blocks, 32/XCD = 4 heads x 8 qt -> K/V 2MB/XCD
    const int id = blockIdx.x;
    const int g  = (id & 7) * 32 + (id >> 3);
    const int qt = g & 7, hb = g >> 3;
    const int h  = hb & 15, b = hb >> 4;
    const int q0 = qt * 256;

    const size_t hsz = (size_t)8 * SEQ * 8;
    const _Float16* kh = Ksw + (size_t)(b * NHEAD + h) * hsz;
    const _Float16* vh = Vsw + (size_t)(b * NHEAD + h) * hsz;

    // Q B-fragments: col=l31 -> q row, k = kk*16 + hi*8 + j  (from compact q_h)
    f16x8 qf[4];
    {
        const int row = q0 + wave * 32 + l31;
        const _Float16* src = Qh + (size_t)(b * SEQ + row) * D_MODEL + h * HDIM + hi * 8;
        #pragma unroll
        for (int kk = 0; kk < 4; ++kk) {
            const f16x8 t = *(const f16x8*)(src + kk * 16);
            #pragma unroll
            for (int j = 0; j < 8; ++j)
                qf[kk][j] = (_Float16)((float)t[j] * 0.1803368802f);   // (1/8)*log2(e)
        }
    }

    f32x16 acc0 = {};      // O[q][d], dtile 0 (d = l31)
    f32x16 acc1 = {};      // dtile 1 (d = 32+l31)
    float rs = 0.f;

    // staging: 8 waves x 2 chunk-instrs each cover sub(2) x chunk(8) for K and V
    // = 4 global_load_lds per thread per 128-key tile.
    const int sidx0 = wave * 2;            // 0..14 even
    // prologue: stage 128-key tile 0 into buffer 0 (no barrier: iter-0 gate covers)
    #pragma unroll
    for (int j = 0; j < 2; ++j) {
        const int idx = sidx0 + j;         // 0..15
        const int u = idx >> 3, c = idx & 7;
        GLOBAL_LOAD_LDS16(kh + ((size_t)c * SEQ + u * 64 + lane) * 8, &Ks[0][idx * 512]);
        GLOBAL_LOAD_LDS16(vh + ((size_t)(u * 8 + c) * HDIM + lane) * 8, &Vts[0][idx * 512]);
    }

    const int NT = SEQ / 128;              // 16
    for (int kt = 0; kt < NT; ++kt) {
        const int cur = kt % 3;

        // stage tile kt+1 into buf (kt+1)%3; then gate: own tile-kt loads
        // (issued last iter / prologue) drained, kt+1's 4 stay in flight.
        // Ring safety: buf[cur] is next write-issued at iter kt+2, after the
        // issuing wave passed barrier(kt+1); readers' ds_reads of buf[cur]
        // are lgkm-drained inside compute(kt), before barrier(kt+1).
        if (kt + 1 < NT) {
            const int nxt = (kt + 1) % 3;
            #pragma unroll
            for (int j = 0; j < 2; ++j) {
                const int idx = sidx0 + j;
                const int u = idx >> 3, c = idx & 7;
                GLOBAL_LOAD_LDS16(kh + ((size_t)c * SEQ + (kt + 1) * 128 + u * 64 + lane) * 8,
                                  &Ks[nxt][idx * 512]);
                GLOBAL_LOAD_LDS16(vh + ((size_t)((kt + 1) * 16 + u * 8 + c) * HDIM + lane) * 8,
                                  &Vts[nxt][idx * 512]);
            }
            asm volatile("s_waitcnt vmcnt(4)" ::: "memory");
        } else {
            asm volatile("s_waitcnt vmcnt(0)" ::: "memory");
        }
        __builtin_amdgcn_s_barrier();
        __builtin_amdgcn_sched_barrier(0);

        // ---- two 64-key subtiles ----
        #pragma unroll
        for (int u = 0; u < 2; ++u) {
            const _Float16* ksub = &Ks[cur][u * 4096];
            const _Float16* vsub = &Vts[cur][u * 4096];

            // QK^T: S^T tiles (keytile 0: keys 0-31, keytile 1: keys 32-63)
            f32x16 s0 = {}, s1 = {};
            __builtin_amdgcn_s_setprio(1);
            #pragma unroll
            for (int kk = 0; kk < 4; ++kk) {
                const f16x8 k0 = *(const f16x8*)&ksub[(kk * 2 + hi) * 512 + l31 * 8];
                const f16x8 k1 = *(const f16x8*)&ksub[(kk * 2 + hi) * 512 + (32 + l31) * 8];
                s0 = __builtin_amdgcn_mfma_f32_32x32x16_f16(k0, qf[kk], s0, 0, 0, 0);
                s1 = __builtin_amdgcn_mfma_f32_32x32x16_f16(k1, qf[kk], s1, 0, 0, 0);
            }
            __builtin_amdgcn_s_setprio(0);

            // exp2 + in-register transpose to PV A-frags
            f16x8 pa[4];
            softmax_frag(s0, s1, rs, pa);

            // PV: O[q][d] += P[q][k] V[k][d], 4 ksteps of 16 keys
            __builtin_amdgcn_s_setprio(1);
            #pragma unroll
            for (int ks = 0; ks < 4; ++ks) {
                const f16x8 v0 = *(const f16x8*)&vsub[(ks * 2 + hi) * 512 + l31 * 8];
                const f16x8 v1 = *(const f16x8*)&vsub[(ks * 2 + hi) * 512 + (32 + l31) * 8];
                acc0 = __builtin_amdgcn_mfma_f32_32x32x16_f16(pa[ks], v0, acc0, 0, 0, 0);
                acc1 = __builtin_amdgcn_mfma_f32_32x32x16_f16(pa[ks], v1, acc1, 0, 0, 0);
            }
            __builtin_amdgcn_s_setprio(0);
        }

        __builtin_amdgcn_sched_barrier(0);   // next iter's stage can't hoist above
    }

    // lane covers half the keys for q=l31; partner lane^32 has the complement
    rs += __shfl_xor(rs, 32);
    const float inv = 1.f / rs;

    #pragma unroll
    for (int r = 0; r < 16; ++r) {
        const int qo = (r & 3) + 8 * (r >> 2) + 4 * hi;     // wave-local q row
        const float invr = __shfl(inv, qo);                  // lane qo holds inv for q=qo
        const int row = b * SEQ + q0 + wave * 32 + qo;
        val[(size_t)row * D_MODEL + h * HDIM + l31]      = (_Float16)(acc0[r] * invr);
        val[(size_t)row * D_MODEL + h * HDIM + 32 + l31] = (_Float16)(acc1[r] * invr);
    }
}

extern "C" void kernel_launch(void* const* d_in, const int* in_sizes, int n_in,
                              void* d_out, int out_size, void* d_ws, size_t ws_size,
                              hipStream_t stream)
{
    const float* x     = (const float*)d_in[0];
    const float* W_qkv = (const float*)d_in[1];
    const float* b_qkv = (const float*)d_in[2];
    const float* W_out = (const float*)d_in[3];
    const float* b_out = (const float*)d_in[4];

    char* ws = (char*)d_ws;
    _Float16* Ksw   = (_Float16*)ws;                      // [32][8][2048][8]  8 MiB
    _Float16* val_h = (_Float16*)(ws + (8u << 20));       // [4096][1024]      8 MiB
    _Float16* wq_t  = (_Float16*)(ws + (16u << 20));      // [3072][1024]      6 MiB
    _Float16* wo_t  = (_Float16*)(ws + (22u << 20));      // [1024][1024]      2 MiB
    _Float16* q_h   = (_Float16*)(ws + (24u << 20));      // [4096][1024]      8 MiB
    _Float16* x_h   = (_Float16*)(ws + (32u << 20));      // [4096][1024]      8 MiB
    _Float16* Vsw   = (_Float16*)(ws + (40u << 20));      // [32][256][64][8]  8 MiB

    prep_kernel<<<5120, 256, 0, stream>>>(x, x_h, W_qkv, wq_t, W_out, wo_t);
    gemm_qkv_kernel<<<dim3(3 * D_MODEL / 128, NTOK / 128), 512, 0, stream>>>(
        x_h, wq_t, b_qkv, q_h, Ksw, Vsw, NTOK, 3 * D_MODEL, D_MODEL);
    attn_mfma_kernel<<<dim3(256, 1, 1), 512, 0, stream>>>(q_h, Ksw, Vsw, val_h);
    gemm_out_kernel<<<dim3(D_MODEL / 64, NTOK / 128), 512, 0, stream>>>(
        val_h, wo_t, b_out, (float*)d_out);
}

// Round 14
// 200.801 us; speedup vs baseline: 1.0263x; 1.0007x over previous
//
#include <hip/hip_runtime.h>

// MultiHeadSelfAttention  B=2 S=2048 D=1024 H=16 d=64, fp32 in/out.
// R21: attn pipeline deepened to 2-tiles-ahead: 4-buffer ring, stage kt+2,
//      gate vmcnt(8) (T4 arithmetic: 4 loads/tile x 2 tiles in flight).
//      Each tile's loads now get 2 full iterations (~4000cy) to land vs 1.
//      Safety: buf[(kt+2)&3] was read at kt-2; readers drained ds_reads in
//      compute(kt-2) before barrier(kt-1); staging wave passes barrier(kt-1)
//      before issuing -> one barrier separates. Tail vmcnt(4)/(0).
//      LDS 96->128KB, still 1 block/CU (grid 256).
//   Why: R20's 1-deep ring banked +2us (wall 201.0 best); 2-deep is the
//   remaining zero-risk step on the same verified structure.
// GEMM1 (R16 counted-vmcnt, ~58us, closed), GEMM2 (R16 dbuf), prep unchanged.
// ws: Ksw 8M @0 | val_h 8M @8 | wq_t 6M @16 | wo_t 2M @22 | q_h 8M @24
//     | x_h 8M @32 | Vsw 8M @40   (total 48M, no aliasing)

#define D_MODEL 1024
#define NHEAD   16
#define HDIM    64
#define SEQ     2048
#define BATCH   2
#define NTOK    (BATCH * SEQ)

typedef float    f32x4  __attribute__((ext_vector_type(4)));
typedef float    f32x16 __attribute__((ext_vector_type(16)));
typedef _Float16 f16x8  __attribute__((ext_vector_type(8)));
typedef _Float16 f16x4  __attribute__((ext_vector_type(4)));

#define GLOBAL_LOAD_LDS16(gptr, lptr)                                            \
    __builtin_amdgcn_global_load_lds(                                            \
        (const __attribute__((address_space(1))) unsigned int*)(gptr),           \
        (__attribute__((address_space(3))) unsigned int*)(lptr), 16, 0, 0)

// ---------------- prep: x->fp16, W_qkv^T, W_out^T (one launch) ----------------
__global__ __launch_bounds__(256) void prep_kernel(
    const float* __restrict__ x, _Float16* __restrict__ xh,
    const float* __restrict__ Wqkv, _Float16* __restrict__ wq_t,
    const float* __restrict__ Wout, _Float16* __restrict__ wo_t)
{
    const int bx = blockIdx.x;
    const int tid = threadIdx.x;
    if (bx < 4096) {
        const int i = (bx * 256 + tid) * 4;
        const float4 v = *(const float4*)&x[i];
        f16x4 hh;
        hh[0] = (_Float16)v.x; hh[1] = (_Float16)v.y;
        hh[2] = (_Float16)v.z; hh[3] = (_Float16)v.w;
        *(f16x4*)&xh[i] = hh;
        return;
    }
    __shared__ float ts[64][65];
    const float* W; _Float16* Wt; int N, n0, k0;
    if (bx < 4096 + 768) {
        const int local = bx - 4096;
        W = Wqkv; Wt = wq_t; N = 3072;
        n0 = (local % 48) * 64; k0 = (local / 48) * 64;
    } else {
        const int local = bx - 4864;
        W = Wout; Wt = wo_t; N = 1024;
        n0 = (local % 16) * 64; k0 = (local / 16) * 64;
    }
    {
        const int r = tid >> 2, c = (tid & 3) << 4;
        const float* src = W + (size_t)(k0 + r) * N + n0 + c;
        #pragma unroll
        for (int u = 0; u < 4; ++u)
            *(float4*)&ts[r][c + u * 4] = *(const float4*)&src[u * 4];
    }
    __syncthreads();
    {
        const int n = tid >> 2, kg = (tid & 3) << 4;
        f16x8 v0, v1;
        #pragma unroll
        for (int j = 0; j < 8; ++j) {
            v0[j] = (_Float16)ts[kg + j][n];
            v1[j] = (_Float16)ts[kg + 8 + j][n];
        }
        _Float16* dst = Wt + (size_t)(n0 + n) * D_MODEL + k0 + kg;
        *(f16x8*)&dst[0] = v0;
        *(f16x8*)&dst[8] = v1;
    }
}

// ---------------- GEMM1: 128x128 tile, BK=32, 512 threads (8 waves of 32x64),
//   3-buffer counted-vmcnt pipeline; epilogue scatters Q/K/V to final layouts -
__global__ __launch_bounds__(512) void gemm_qkv_kernel(
    const _Float16* __restrict__ A, const _Float16* __restrict__ Bt,
    const float* __restrict__ bias, _Float16* __restrict__ Qh,
    _Float16* __restrict__ Ksw, _Float16* __restrict__ Vsw,
    int M, int N, int K)
{
    __shared__ _Float16 lds[3][2][4096];  // [buf3][plane A/B][chunk4][row128][8] 48KB
    const int tid = threadIdx.x;
    const int wave = tid >> 6, lane = tid & 63;
    const int quad = lane >> 4, l16 = lane & 15;
    const int m0 = blockIdx.y * 128, n0 = blockIdx.x * 128;
    const int wr = wave >> 1, wc = wave & 1;       // wave tile: rows wr*32, cols wc*64

    f32x4 acc[2][4] = {};

    const bool isA = wave < 4;
    const _Float16* gsrc = isA ? (A + (size_t)m0 * K) : (Bt + (size_t)n0 * K);
    const int plane = isA ? 0 : 1;
    const int sbase = (wave & 3) * 2;              // 2 segments of 1KB per wave

#define G1_STAGE(tt, bi) {                                                     \
        const int _k1 = (tt) * 32;                                             \
        _Pragma("unroll")                                                      \
        for (int _j = 0; _j < 2; ++_j) {                                       \
            const int _seg = sbase + _j;                                       \
            const int _row = ((_seg & 1) << 6) | lane;                         \
            GLOBAL_LOAD_LDS16(gsrc + (size_t)_row * K + _k1 + (_seg >> 1) * 8, \
                              &lds[bi][plane][_seg * 512]);                    \
        } }

#define G1_COMPUTE(bi) {                                                       \
        f16x8 a[2], b[4];                                                      \
        _Pragma("unroll")                                                      \
        for (int mt = 0; mt < 2; ++mt)                                         \
            a[mt] = *(const f16x8*)&lds[bi][0][quad * 1024 + (wr * 32 + mt * 16 + l16) * 8]; \
        _Pragma("unroll")                                                      \
        for (int nt = 0; nt < 4; ++nt)                                         \
            b[nt] = *(const f16x8*)&lds[bi][1][quad * 1024 + (wc * 64 + nt * 16 + l16) * 8]; \
        __builtin_amdgcn_s_setprio(1);                                         \
        _Pragma("unroll")                                                      \
        for (int mt = 0; mt < 2; ++mt)                                         \
            _Pragma("unroll")                                                  \
            for (int nt = 0; nt < 4; ++nt)                                     \
                acc[mt][nt] = __builtin_amdgcn_mfma_f32_16x16x32_f16(a[mt], b[nt], acc[mt][nt], 0, 0, 0); \
        __builtin_amdgcn_s_setprio(0); }

#define G1_KSTEP(t, gatestr) {                                                 \
        const int _cur = (t) % 3;                                              \
        if ((t) + 2 < nk) { G1_STAGE((t) + 2, ((t) + 2) % 3); }                \
        asm volatile("s_waitcnt " gatestr ::: "memory");                       \
        __builtin_amdgcn_s_barrier();                                          \
        __builtin_amdgcn_sched_barrier(0);                                     \
        G1_COMPUTE(_cur);                                                      \
        __builtin_amdgcn_sched_barrier(0);                                     \
        __builtin_amdgcn_s_barrier();                                          \
        __builtin_amdgcn_sched_barrier(0);                                     \
    }

    const int nk = K / 32;                 // 32
    G1_STAGE(0, 0);
    G1_STAGE(1, 1);

    for (int t = 0; t < nk - 2; ++t)
        G1_KSTEP(t, "vmcnt(4)");
    G1_KSTEP(nk - 2, "vmcnt(2)");
    G1_KSTEP(nk - 1, "vmcnt(0)");

#undef G1_KSTEP
#undef G1_COMPUTE
#undef G1_STAGE

    // ---- epilogue: 64-col region (64-aligned) mod 192 selects Q/K/V of head h
    const int colb = n0 + wc * 64;
    const int kind = (colb >> 6) % 3;      // 0=Q, 1=K, 2=V
    const int h    = colb / 192;
    const int bb   = m0 >> 11;             // batch (128-row tile within one batch)
    const int m0r  = m0 & 2047;            // s base within batch
    const size_t hsz = (size_t)8 * SEQ * 8;

    if (kind == 0) {
        // Q -> q_h[4096][1024]: row-major, head-compacted
        _Float16* qh = Qh + (size_t)m0 * D_MODEL + h * HDIM;
        #pragma unroll
        for (int nt = 0; nt < 4; ++nt) {
            const float bv = bias[colb + nt * 16 + l16];
            #pragma unroll
            for (int mt = 0; mt < 2; ++mt) {
                #pragma unroll
                for (int r = 0; r < 4; ++r) {
                    const int row = wr * 32 + mt * 16 + quad * 4 + r;
                    qh[(size_t)row * D_MODEL + nt * 16 + l16] = (_Float16)(acc[mt][nt][r] + bv);
                }
            }
        }
    } else if (kind == 1) {
        // K(s,d) -> kh[(d>>3)*SEQ*8 + s*8 + (d&7)]
        _Float16* kh = Ksw + (size_t)(bb * NHEAD + h) * hsz;
        #pragma unroll
        for (int nt = 0; nt < 4; ++nt) {
            const int d = nt * 16 + l16;
            const float bv = bias[colb + nt * 16 + l16];
            _Float16* kd = kh + (size_t)(d >> 3) * (SEQ * 8) + (d & 7);
            #pragma unroll
            for (int mt = 0; mt < 2; ++mt) {
                #pragma unroll
                for (int r = 0; r < 4; ++r) {
                    const int s = m0r + wr * 32 + mt * 16 + quad * 4 + r;
                    kd[(size_t)s * 8] = (_Float16)(acc[mt][nt][r] + bv);
                }
            }
        }
    } else {
        // V(s,d) -> vh[(s>>3)*512 + d*8 + (s&7)]; 4 acc rows = contiguous f16x4
        _Float16* vh = Vsw + (size_t)(bb * NHEAD + h) * hsz;
        #pragma unroll
        for (int nt = 0; nt < 4; ++nt) {
            const int d = nt * 16 + l16;
            const float bv = bias[colb + nt * 16 + l16];
            #pragma unroll
            for (int mt = 0; mt < 2; ++mt) {
                const int s0 = m0r + wr * 32 + mt * 16 + quad * 4;
                f16x4 pk;
                #pragma unroll
                for (int r = 0; r < 4; ++r)
                    pk[r] = (_Float16)(acc[mt][nt][r] + bv);
                *(f16x4*)&vh[(size_t)(s0 >> 3) * 512 + d * 8 + (s0 & 7)] = pk;
            }
        }
    }
}

// ---------------- GEMM2: 128x64 tile, BK=32, 512 threads (8 waves of 32x32),
//                  double-buffered staging, one barrier per K-step, fp32 out --
__global__ __launch_bounds__(512) void gemm_out_kernel(
    const _Float16* __restrict__ A, const _Float16* __restrict__ Bt,
    const float* __restrict__ bias, float* __restrict__ Cout)
{
    const int K = D_MODEL, N = D_MODEL;
    __shared__ _Float16 ldsA[2][4096];    // [buf][chunk4][row128][8] 8KB x2
    __shared__ _Float16 ldsB[2][2048];    // [buf][chunk4][row64][8]  4KB x2
    const int tid = threadIdx.x;
    const int wave = tid >> 6, lane = tid & 63;
    const int quad = lane >> 4, l16 = lane & 15;
    const int m0 = blockIdx.y * 128, n0 = blockIdx.x * 64;
    const int wr = wave >> 1, wc = wave & 1;       // wave tile: rows wr*32, cols wc*32

    f32x4 acc[2][2] = {};

    // prologue: stage K-tile 0 into buf 0
    if (wave < 4) {
        #pragma unroll
        for (int j = 0; j < 2; ++j) {
            const int seg = wave * 2 + j;
            const int chunk = seg >> 1;
            const int row = ((seg & 1) << 6) | lane;
            GLOBAL_LOAD_LDS16(A + (size_t)(m0 + row) * K + chunk * 8, &ldsA[0][seg * 512]);
        }
    } else {
        const int seg = wave - 4;
        GLOBAL_LOAD_LDS16(Bt + (size_t)(n0 + lane) * K + seg * 8, &ldsB[0][seg * 512]);
    }
    __syncthreads();

    const int nk = K / 32;
    for (int t = 0; t < nk; ++t) {
        const int cur = t & 1;

        if (t + 1 < nk) {
            const int k1 = (t + 1) * 32;
            if (wave < 4) {
                #pragma unroll
                for (int j = 0; j < 2; ++j) {
                    const int seg = wave * 2 + j;
                    const int chunk = seg >> 1;
                    const int row = ((seg & 1) << 6) | lane;
                    GLOBAL_LOAD_LDS16(A + (size_t)(m0 + row) * K + k1 + chunk * 8,
                                      &ldsA[cur ^ 1][seg * 512]);
                }
            } else {
                const int seg = wave - 4;
                GLOBAL_LOAD_LDS16(Bt + (size_t)(n0 + lane) * K + k1 + seg * 8,
                                  &ldsB[cur ^ 1][seg * 512]);
            }
        }

        f16x8 a[2], b[2];
        #pragma unroll
        for (int mt = 0; mt < 2; ++mt)
            a[mt] = *(const f16x8*)&ldsA[cur][quad * 1024 + (wr * 32 + mt * 16 + l16) * 8];
        #pragma unroll
        for (int nt = 0; nt < 2; ++nt)
            b[nt] = *(const f16x8*)&ldsB[cur][quad * 512 + (wc * 32 + nt * 16 + l16) * 8];
        #pragma unroll
        for (int mt = 0; mt < 2; ++mt)
            #pragma unroll
            for (int nt = 0; nt < 2; ++nt)
                acc[mt][nt] = __builtin_amdgcn_mfma_f32_16x16x32_f16(a[mt], b[nt], acc[mt][nt], 0, 0, 0);

        __syncthreads();
    }

    #pragma unroll
    for (int nt = 0; nt < 2; ++nt) {
        const int col = n0 + wc * 32 + nt * 16 + l16;
        const float bv = bias[col];
        #pragma unroll
        for (int mt = 0; mt < 2; ++mt) {
            #pragma unroll
            for (int r = 0; r < 4; ++r) {
                const int row = m0 + wr * 32 + mt * 16 + quad * 4 + r;
                Cout[(size_t)row * N + col] = acc[mt][nt][r] + bv;
            }
        }
    }
}

// softmax fragment: s0/s1 (keys 0-31 / 32-63 scores for q=l31) -> 4 PV A-frags
// pa[ks][j] = P[q=l31][key = ks*16 + hi*8 + j], rs += sum of own 32 exp2's.
__device__ __forceinline__ void softmax_frag(
    const f32x16 s0, const f32x16 s1, float& rs, f16x8 pa[4])
{
    #pragma unroll
    for (int half = 0; half < 2; ++half) {
        const f32x16 sv = half ? s1 : s0;
        float p[16];
        #pragma unroll
        for (int r = 0; r < 16; ++r)
            p[r] = __builtin_amdgcn_exp2f(sv[r]);
        #pragma unroll
        for (int r = 0; r < 16; r += 4)
            rs += (p[r] + p[r + 1]) + (p[r + 2] + p[r + 3]);

        union { f16x8 hv; unsigned u[4]; } lo, hh;
        {
            const unsigned A = __builtin_bit_cast(unsigned, __builtin_amdgcn_cvt_pkrtz(p[0], p[1]));
            const unsigned B = __builtin_bit_cast(unsigned, __builtin_amdgcn_cvt_pkrtz(p[2], p[3]));
            const unsigned C = __builtin_bit_cast(unsigned, __builtin_amdgcn_cvt_pkrtz(p[4], p[5]));
            const unsigned D = __builtin_bit_cast(unsigned, __builtin_amdgcn_cvt_pkrtz(p[6], p[7]));
            const auto rac = __builtin_amdgcn_permlane32_swap(A, C, false, false);
            const auto rbd = __builtin_amdgcn_permlane32_swap(B, D, false, false);
            lo.u[0] = rac[0]; lo.u[1] = rbd[0]; lo.u[2] = rac[1]; lo.u[3] = rbd[1];
        }
        {
            const unsigned E = __builtin_bit_cast(unsigned, __builtin_amdgcn_cvt_pkrtz(p[8],  p[9]));
            const unsigned F = __builtin_bit_cast(unsigned, __builtin_amdgcn_cvt_pkrtz(p[10], p[11]));
            const unsigned G = __builtin_bit_cast(unsigned, __builtin_amdgcn_cvt_pkrtz(p[12], p[13]));
            const unsigned H = __builtin_bit_cast(unsigned, __builtin_amdgcn_cvt_pkrtz(p[14], p[15]));
            const auto reg = __builtin_amdgcn_permlane32_swap(E, G, false, false);
            const auto rfh = __builtin_amdgcn_permlane32_swap(F, H, false, false);
            hh.u[0] = reg[0]; hh.u[1] = rfh[0]; hh.u[2] = reg[1]; hh.u[3] = rfh[1];
        }
        pa[half * 2]     = lo.hv;
        pa[half * 2 + 1] = hh.hv;
    }
}

// ---------------- fp16 MFMA flash attention, 32x32, QBLK=256 (8 waves x 32q),
//   KVBLK=128, 4-buffer ring + 2-ahead prefetch + counted vmcnt(8),
//   ONE raw barrier per tile ---------------------------------------------------
__global__ __launch_bounds__(512) void attn_mfma_kernel(
    const _Float16* __restrict__ Qh,
    const _Float16* __restrict__ Ksw, const _Float16* __restrict__ Vsw,
    _Float16* __restrict__ val)
{
    __shared__ _Float16 Ks[4][8192];      // [buf4][sub2][dchunk8][key64][8]  64KB
    __shared__ _Float16 Vts[4][8192];     // [buf4][sub2][kchunk8][d64][8]    64KB

    const int tid = threadIdx.x;
    const int wave = tid >> 6, lane = tid & 63;
    const int l31 = lane & 31, hi = lane >> 5;

    // XCD-chunked swizzle: 256 blocks, 32/XCD = 4 heads x 8 qt -> K/V 2MB/XCD
    const int id = blockIdx.x;
    const int g  = (id & 7) * 32 + (id >> 3);
    const int qt = g & 7, hb = g >> 3;
    const int h  = hb & 15, b = hb >> 4;
    const int q0 = qt * 256;

    const size_t hsz = (size_t)8 * SEQ * 8;
    const _Float16* kh = Ksw + (size_t)(b * NHEAD + h) * hsz;
    const _Float16* vh = Vsw + (size_t)(b * NHEAD + h) * hsz;

    // Q B-fragments: col=l31 -> q row, k = kk*16 + hi*8 + j  (from compact q_h)
    f16x8 qf[4];
    {
        const int row = q0 + wave * 32 + l31;
        const _Float16* src = Qh + (size_t)(b * SEQ + row) * D_MODEL + h * HDIM + hi * 8;
        #pragma unroll
        for (int kk = 0; kk < 4; ++kk) {
            const f16x8 t = *(const f16x8*)(src + kk * 16);
            #pragma unroll
            for (int j = 0; j < 8; ++j)
                qf[kk][j] = (_Float16)((float)t[j] * 0.1803368802f);   // (1/8)*log2(e)
        }
    }

    f32x16 acc0 = {};      // O[q][d], dtile 0 (d = l31)
    f32x16 acc1 = {};      // dtile 1 (d = 32+l31)
    float rs = 0.f;

    // staging: 8 waves x 2 chunk-instrs each cover sub(2) x chunk(8) for K and V
    // = 4 global_load_lds per thread per 128-key tile.
    const int sidx0 = wave * 2;            // 0..14 even

#define ATTN_STAGE(tt, bi) {                                                   \
        _Pragma("unroll")                                                      \
        for (int _j = 0; _j < 2; ++_j) {                                       \
            const int _idx = sidx0 + _j;                                       \
            const int _u = _idx >> 3, _c = _idx & 7;                           \
            GLOBAL_LOAD_LDS16(kh + ((size_t)_c * SEQ + (tt) * 128 + _u * 64 + lane) * 8, \
                              &Ks[bi][_idx * 512]);                            \
            GLOBAL_LOAD_LDS16(vh + ((size_t)((tt) * 16 + _u * 8 + _c) * HDIM + lane) * 8, \
                              &Vts[bi][_idx * 512]);                           \
        } }

    // prologue: stage tiles 0,1 into bufs 0,1 (no barrier: iter-0 gate covers)
    ATTN_STAGE(0, 0);
    ATTN_STAGE(1, 1);

    const int NT = SEQ / 128;              // 16
    for (int kt = 0; kt < NT; ++kt) {
        const int cur = kt & 3;

        // stage tile kt+2 into buf (kt+2)&3 (2-ahead); gate: own tile-kt
        // loads drained, tiles kt+1 & kt+2 (4+4) stay in flight.
        // Ring safety: buf[(kt+2)&3] was read at iter kt-2; its readers'
        // ds_reads drained inside compute(kt-2), before barrier(kt-1);
        // this staging wave passed barrier(kt-1) before issuing.
        if (kt + 2 < NT) {
            ATTN_STAGE(kt + 2, (kt + 2) & 3);
            asm volatile("s_waitcnt vmcnt(8)" ::: "memory");
        } else if (kt + 1 < NT) {
            asm volatile("s_waitcnt vmcnt(4)" ::: "memory");
        } else {
            asm volatile("s_waitcnt vmcnt(0)" ::: "memory");
        }
        __builtin_amdgcn_s_barrier();
        __builtin_amdgcn_sched_barrier(0);

        // ---- two 64-key subtiles ----
        #pragma unroll
        for (int u = 0; u < 2; ++u) {
            const _Float16* ksub = &Ks[cur][u * 4096];
            const _Float16* vsub = &Vts[cur][u * 4096];

            // QK^T: S^T tiles (keytile 0: keys 0-31, keytile 1: keys 32-63)
            f32x16 s0 = {}, s1 = {};
            __builtin_amdgcn_s_setprio(1);
            #pragma unroll
            for (int kk = 0; kk < 4; ++kk) {
                const f16x8 k0 = *(const f16x8*)&ksub[(kk * 2 + hi) * 512 + l31 * 8];
                const f16x8 k1 = *(const f16x8*)&ksub[(kk * 2 + hi) * 512 + (32 + l31) * 8];
                s0 = __builtin_amdgcn_mfma_f32_32x32x16_f16(k0, qf[kk], s0, 0, 0, 0);
                s1 = __builtin_amdgcn_mfma_f32_32x32x16_f16(k1, qf[kk], s1, 0, 0, 0);
            }
            __builtin_amdgcn_s_setprio(0);

            // exp2 + in-register transpose to PV A-frags
            f16x8 pa[4];
            softmax_frag(s0, s1, rs, pa);

            // PV: O[q][d] += P[q][k] V[k][d], 4 ksteps of 16 keys
            __builtin_amdgcn_s_setprio(1);
            #pragma unroll
            for (int ks = 0; ks < 4; ++ks) {
                const f16x8 v0 = *(const f16x8*)&vsub[(ks * 2 + hi) * 512 + l31 * 8];
                const f16x8 v1 = *(const f16x8*)&vsub[(ks * 2 + hi) * 512 + (32 + l31) * 8];
                acc0 = __builtin_amdgcn_mfma_f32_32x32x16_f16(pa[ks], v0, acc0, 0, 0, 0);
                acc1 = __builtin_amdgcn_mfma_f32_32x32x16_f16(pa[ks], v1, acc1, 0, 0, 0);
            }
            __builtin_amdgcn_s_setprio(0);
        }

        __builtin_amdgcn_sched_barrier(0);   // next iter's stage can't hoist above
    }
#undef ATTN_STAGE

    // lane covers half the keys for q=l31; partner lane^32 has the complement
    rs += __shfl_xor(rs, 32);
    const float inv = 1.f / rs;

    #pragma unroll
    for (int r = 0; r < 16; ++r) {
        const int qo = (r & 3) + 8 * (r >> 2) + 4 * hi;     // wave-local q row
        const float invr = __shfl(inv, qo);                  // lane qo holds inv for q=qo
        const int row = b * SEQ + q0 + wave * 32 + qo;
        val[(size_t)row * D_MODEL + h * HDIM + l31]      = (_Float16)(acc0[r] * invr);
        val[(size_t)row * D_MODEL + h * HDIM + 32 + l31] = (_Float16)(acc1[r] * invr);
    }
}

extern "C" void kernel_launch(void* const* d_in, const int* in_sizes, int n_in,
                              void* d_out, int out_size, void* d_ws, size_t ws_size,
                              hipStream_t stream)
{
    const float* x     = (const float*)d_in[0];
    const float* W_qkv = (const float*)d_in[1];
    const float* b_qkv = (const float*)d_in[2];
    const float* W_out = (const float*)d_in[3];
    const float* b_out = (const float*)d_in[4];

    char* ws = (char*)d_ws;
    _Float16* Ksw   = (_Float16*)ws;                      // [32][8][2048][8]  8 MiB
    _Float16* val_h = (_Float16*)(ws + (8u << 20));       // [4096][1024]      8 MiB
    _Float16* wq_t  = (_Float16*)(ws + (16u << 20));      // [3072][1024]      6 MiB
    _Float16* wo_t  = (_Float16*)(ws + (22u << 20));      // [1024][1024]      2 MiB
    _Float16* q_h   = (_Float16*)(ws + (24u << 20));      // [4096][1024]      8 MiB
    _Float16* x_h   = (_Float16*)(ws + (32u << 20));      // [4096][1024]      8 MiB
    _Float16* Vsw   = (_Float16*)(ws + (40u << 20));      // [32][256][64][8]  8 MiB

    prep_kernel<<<5120, 256, 0, stream>>>(x, x_h, W_qkv, wq_t, W_out, wo_t);
    gemm_qkv_kernel<<<dim3(3 * D_MODEL / 128, NTOK / 128), 512, 0, stream>>>(
        x_h, wq_t, b_qkv, q_h, Ksw, Vsw, NTOK, 3 * D_MODEL, D_MODEL);
    attn_mfma_kernel<<<dim3(256, 1, 1), 512, 0, stream>>>(q_h, Ksw, Vsw, val_h);
    gemm_out_kernel<<<dim3(D_MODEL / 64, NTOK / 128), 512, 0, stream>>>(
        val_h, wo_t, b_out, (float*)d_out);
}